// Round 20
// baseline (882.153 us; speedup 1.0000x reference)
//
#include <hip/hip_runtime.h>
#include <hip/hip_bf16.h>
#include <stdint.h>

#define IN_SZ   256
#define OUT_SZ  256
#define RANK    60
#define NSEL    256
#define BATCH   1024
#define WELEMS  (IN_SZ * OUT_SZ)   // 65536 elems per channel

typedef __attribute__((ext_vector_type(8))) short          short8;
typedef __attribute__((ext_vector_type(4))) float          f32x4;

static __device__ __forceinline__ unsigned short f32_to_bf16(float f) {
    union { float f; uint32_t u; } c; c.f = f;
    uint32_t u = c.u;
    u += 0x7fffu + ((u >> 16) & 1u);   // RNE
    return (unsigned short)(u >> 16);
}

// pair-packed RNE convert — compiler emits v_cvt_pk_bf16_f32 (same rounding)
static __device__ __forceinline__ short8 cvt8(f32x4 lo, f32x4 hi) {
    union { short8 s; __hip_bfloat162 h[4]; } u;
    u.h[0] = __float22bfloat162_rn(make_float2(lo[0], lo[1]));
    u.h[1] = __float22bfloat162_rn(make_float2(lo[2], lo[3]));
    u.h[2] = __float22bfloat162_rn(make_float2(hi[0], hi[1]));
    u.h[3] = __float22bfloat162_rn(make_float2(hi[2], hi[3]));
    return u.s;
}

// -----------------------------------------------------------------------------
// Kernel 1: W_sel = U[idx] @ V -> bf16 in B-FRAGMENT-MAJOR layout:
//   wt[n][koct*2048 + o*8 + il]   (koct = i>>3, il = i&7)
// (unchanged — verified correct, ~24 µs)
// -----------------------------------------------------------------------------
__global__ __launch_bounds__(256) void synth_w(
    const float* __restrict__ U, const float* __restrict__ V,
    const int* __restrict__ idx, unsigned short* __restrict__ wt)
{
    __shared__ unsigned short Cs[16][2064];

    int bid = blockIdx.x;                  // 512 blocks
    int L   = (bid & 7) * 64 + (bid >> 3); // XCD swizzle: same-ic -> same XCD
    int ic  = L >> 4;
    int g16 = L & 15;

    int tid = threadIdx.x, lane = tid & 63, wv = tid >> 6;

    int arow = lane & 15;
    int c    = idx[g16 * 16 + arow];
    short8 afr[2];
    #pragma unroll
    for (int ks = 0; ks < 2; ++ks) {
        short8 h;
        #pragma unroll
        for (int j = 0; j < 8; ++j) {
            int r = ks * 32 + (lane >> 4) * 8 + j;
            float u = (r < RANK) ? U[c * RANK + r] : 0.f;
            h[j] = (short)f32_to_bf16(u);
        }
        afr[ks] = h;
    }

    const float* Vb = V + (size_t)ic * 2048;
    #pragma unroll 2
    for (int mt = 0; mt < 32; ++mt) {
        int mloc = (wv * 32 + mt) * 16 + (lane & 15);
        f32x4 acc = {};
        #pragma unroll
        for (int ks = 0; ks < 2; ++ks) {
            short8 b;
            #pragma unroll
            for (int j = 0; j < 8; ++j) {
                int r = ks * 32 + (lane >> 4) * 8 + j;
                float v = (r < RANK) ? Vb[(size_t)r * WELEMS + mloc] : 0.f;
                b[j] = (short)f32_to_bf16(v);
            }
            acc = __builtin_amdgcn_mfma_f32_16x16x32_bf16(afr[ks], b, acc, 0, 0, 0);
        }
        #pragma unroll
        for (int j = 0; j < 4; ++j) {
            int nl = (lane >> 4) * 4 + j;
            Cs[nl][wv * 512 + mt * 16 + (lane & 15)] = f32_to_bf16(acc[j]);
        }
    }
    __syncthreads();

    #pragma unroll
    for (int t0 = 0; t0 < 16; ++t0) {
        int t  = t0 * 256 + tid;
        int nl = t >> 8;
        int o  = t & 255;
        short8 h;
        #pragma unroll
        for (int il = 0; il < 8; ++il) h[il] = (short)Cs[nl][il * 256 + o];
        int n = g16 * 16 + nl;
        size_t base = (size_t)n * WELEMS + (size_t)ic * 2048 + (size_t)o * 8;
        *reinterpret_cast<short8*>(wt + base) = h;
    }
}

// -----------------------------------------------------------------------------
// Kernel 2: W-RESIDENT-IN-LDS GEMM, 16 waves (4/SIMD TLP), register-budgeted.
// One block per n (256 blocks, 1024 threads). W[n] 128 KB in LDS + bias; ONE
// barrier; free-running waves, each owning 64 rows (4 tiles of 16).
// A pipeline at QUARTER-tile (2 ks) granularity:
//   F f32 dbuf (32 regs) issued 3 steps ahead; cvt to Pa/Pb short8 (8 regs)
//   one step before use -> distance-2 vmcnt wait, ~half R15's A-register cost.
// Demand ~122 regs; amdgpu_waves_per_eu(4,4) pins the budget to exactly 128
// (R19: allocator targeted 8/EU, budgeted 64, spilled 188 MB).
// -----------------------------------------------------------------------------
__global__ __launch_bounds__(1024)
__attribute__((amdgpu_waves_per_eu(4, 4)))
void gemm_k(
    const float* __restrict__ x, const int* __restrict__ idx,
    const unsigned short* __restrict__ wt, const float* __restrict__ bias,
    float* __restrict__ out)
{
    __shared__ __align__(16) unsigned short Wl[WELEMS];   // 128 KB
    __shared__ __align__(16) float          Bl[256];      // 1 KB bias

    int n    = blockIdx.x;                 // 0..255, one n per block
    int tid  = threadIdx.x;
    int lane = tid & 63;
    int wv   = tid >> 6;                   // 0..15
    int r16  = lane & 15;
    int q    = lane >> 4;

    const unsigned short* wn = wt + (size_t)n * WELEMS;

    // ---- stage W[n]: 128 x 1KB linear DMA segments (8 per wave) ----
    #pragma unroll
    for (int j = 0; j < 8; ++j) {
        int g = wv * 8 + j;                // 0..127
        __builtin_amdgcn_global_load_lds(
            (const __attribute__((address_space(1))) void*)(wn + g * 512 + lane * 8),
            (__attribute__((address_space(3))) void*)(&Wl[g * 512]),
            16, 0, 0);
    }
    // ---- stage bias[c] ----
    int c = idx[n];
    if (tid < 64) {
        f32x4 b = *reinterpret_cast<const f32x4*>(bias + (size_t)c * OUT_SZ + tid * 4);
        *reinterpret_cast<f32x4*>(&Bl[tid * 4]) = b;
    }
    __syncthreads();   // the only barrier (drains DMA + ds_write)

    const float* xw = x + (size_t)n * (BATCH * IN_SZ)
                        + (size_t)(wv * 64 + r16) * IN_SZ + q * 8;
    float*       ow = out + (size_t)n * (BATCH * OUT_SZ)
                        + (size_t)(wv * 64 + r16) * OUT_SZ + q * 4;
    const char*  wl = reinterpret_cast<const char*>(Wl);
    int lq = q * 4096 + r16 * 16;          // lane's byte base into Wl (conflict-free)

    // quarter-step d = 4*t + qs  (t = 16-row chunk 0..3, qs = 2-ks quarter 0..3)
    f32x4  F0[2][2], F1[2][2];             // f32 staging, 16 regs each
    short8 Pa[2], Pb[2];                   // bf16 fragments, 4 regs each

    auto issueQ = [&](f32x4 (&F)[2][2], int d) {
        const float* xp = xw + (size_t)(d >> 2) * 16 * IN_SZ + (d & 3) * 64;
        #pragma unroll
        for (int k2 = 0; k2 < 2; ++k2) {
            F[k2][0] = *reinterpret_cast<const f32x4*>(xp + k2 * 32);
            F[k2][1] = *(reinterpret_cast<const f32x4*>(xp + k2 * 32) + 1);
        }
    };
    auto cvtQ = [&](short8 (&P)[2], f32x4 (&F)[2][2]) {
        P[0] = cvt8(F[0][0], F[0][1]);
        P[1] = cvt8(F[1][0], F[1][1]);
    };

    // prologue
    issueQ(F0, 0);
    issueQ(F1, 1);
    cvtQ(Pa, F0);          // waits d0 (d1 stays in flight)
    issueQ(F0, 2);

    f32x4 acc[16];

    #pragma unroll
    for (int s = 0; s < 16; ++s) {
        if ((s & 3) == 0) {                // new tile: acc init = bias
            #pragma unroll
            for (int nf = 0; nf < 16; ++nf)
                acc[nf] = *reinterpret_cast<const f32x4*>(&Bl[nf * 16 + q * 4]);
        }

        short8 (&Pc)[2] = (s & 1) ? Pb : Pa;     // static after unroll
        short8 (&Pn)[2] = (s & 1) ? Pa : Pb;

        #pragma unroll
        for (int k2 = 0; k2 < 2; ++k2) {
            int ks = (s & 3) * 2 + k2;
            short8 af = Pc[k2];
            #pragma unroll
            for (int nf = 0; nf < 16; ++nf) {
                short8 bf = *reinterpret_cast<const short8*>(
                    wl + lq + ks * 16384 + nf * 256);
                acc[nf] = __builtin_amdgcn_mfma_f32_16x16x32_bf16(
                    bf, af, acc[nf], 0, 0, 0);   // swapped: out^T frag
            }
        }

        if (s < 15) {                      // prep next quarter
            if (s & 1) { cvtQ(Pn, F0); if (s < 13) issueQ(F0, s + 3); }
            else       { cvtQ(Pn, F1); if (s < 13) issueQ(F1, s + 3); }
        }

        if ((s & 3) == 3) {                // tile finished: store 16 x 256
            float* op = ow + (size_t)(s >> 2) * 16 * OUT_SZ;
            #pragma unroll
            for (int nf = 0; nf < 16; ++nf)
                *reinterpret_cast<f32x4*>(op + nf * 16) = acc[nf];
        }
    }
}

extern "C" void kernel_launch(void* const* d_in, const int* in_sizes, int n_in,
                              void* d_out, int out_size, void* d_ws, size_t ws_size,
                              hipStream_t stream) {
    const float* x    = (const float*)d_in[0];
    const int*   idx  = (const int*)  d_in[1];
    const float* U    = (const float*)d_in[2];
    const float* V    = (const float*)d_in[3];
    const float* bias = (const float*)d_in[4];
    float* out = (float*)d_out;
    unsigned short* wt = (unsigned short*)d_ws;   // 32 MB scratch
    (void)in_sizes; (void)n_in; (void)out_size; (void)ws_size;

    synth_w<<<dim3(512), dim3(256), 0, stream>>>(U, V, idx, wt);
    gemm_k <<<dim3(256), dim3(1024), 0, stream>>>(x, idx, wt, bias, out);
}

// Round 21
// 170.199 us; speedup vs baseline: 5.1831x; 5.1831x over previous
//
#include <hip/hip_runtime.h>
#include <hip/hip_bf16.h>
#include <stdint.h>

#define IN_SZ   256
#define OUT_SZ  256
#define RANK    60
#define NSEL    256
#define BATCH   1024
#define WELEMS  (IN_SZ * OUT_SZ)   // 65536 elems per channel

typedef __attribute__((ext_vector_type(8))) short          short8;
typedef __attribute__((ext_vector_type(4))) float          f32x4;

static __device__ __forceinline__ unsigned short f32_to_bf16(float f) {
    union { float f; uint32_t u; } c; c.f = f;
    uint32_t u = c.u;
    u += 0x7fffu + ((u >> 16) & 1u);   // RNE
    return (unsigned short)(u >> 16);
}

// pair-packed RNE convert — compiler emits v_cvt_pk_bf16_f32 (same rounding)
static __device__ __forceinline__ short8 cvt8(f32x4 lo, f32x4 hi) {
    union { short8 s; __hip_bfloat162 h[4]; } u;
    u.h[0] = __float22bfloat162_rn(make_float2(lo[0], lo[1]));
    u.h[1] = __float22bfloat162_rn(make_float2(lo[2], lo[3]));
    u.h[2] = __float22bfloat162_rn(make_float2(hi[0], hi[1]));
    u.h[3] = __float22bfloat162_rn(make_float2(hi[2], hi[3]));
    return u.s;
}

// -----------------------------------------------------------------------------
// Kernel 1: W_sel = U[idx] @ V -> bf16 in B-FRAGMENT-MAJOR layout:
//   wt[n][koct*2048 + o*8 + il]   (koct = i>>3, il = i&7)
// (unchanged — verified correct, ~24 µs)
// -----------------------------------------------------------------------------
__global__ __launch_bounds__(256) void synth_w(
    const float* __restrict__ U, const float* __restrict__ V,
    const int* __restrict__ idx, unsigned short* __restrict__ wt)
{
    __shared__ unsigned short Cs[16][2064];

    int bid = blockIdx.x;                  // 512 blocks
    int L   = (bid & 7) * 64 + (bid >> 3); // XCD swizzle: same-ic -> same XCD
    int ic  = L >> 4;
    int g16 = L & 15;

    int tid = threadIdx.x, lane = tid & 63, wv = tid >> 6;

    int arow = lane & 15;
    int c    = idx[g16 * 16 + arow];
    short8 afr[2];
    #pragma unroll
    for (int ks = 0; ks < 2; ++ks) {
        short8 h;
        #pragma unroll
        for (int j = 0; j < 8; ++j) {
            int r = ks * 32 + (lane >> 4) * 8 + j;
            float u = (r < RANK) ? U[c * RANK + r] : 0.f;
            h[j] = (short)f32_to_bf16(u);
        }
        afr[ks] = h;
    }

    const float* Vb = V + (size_t)ic * 2048;
    #pragma unroll 2
    for (int mt = 0; mt < 32; ++mt) {
        int mloc = (wv * 32 + mt) * 16 + (lane & 15);
        f32x4 acc = {};
        #pragma unroll
        for (int ks = 0; ks < 2; ++ks) {
            short8 b;
            #pragma unroll
            for (int j = 0; j < 8; ++j) {
                int r = ks * 32 + (lane >> 4) * 8 + j;
                float v = (r < RANK) ? Vb[(size_t)r * WELEMS + mloc] : 0.f;
                b[j] = (short)f32_to_bf16(v);
            }
            acc = __builtin_amdgcn_mfma_f32_16x16x32_bf16(afr[ks], b, acc, 0, 0, 0);
        }
        #pragma unroll
        for (int j = 0; j < 4; ++j) {
            int nl = (lane >> 4) * 4 + j;
            Cs[nl][wv * 512 + mt * 16 + (lane & 15)] = f32_to_bf16(acc[j]);
        }
    }
    __syncthreads();

    #pragma unroll
    for (int t0 = 0; t0 < 16; ++t0) {
        int t  = t0 * 256 + tid;
        int nl = t >> 8;
        int o  = t & 255;
        short8 h;
        #pragma unroll
        for (int il = 0; il < 8; ++il) h[il] = (short)Cs[nl][il * 256 + o];
        int n = g16 * 16 + nl;
        size_t base = (size_t)n * WELEMS + (size_t)ic * 2048 + (size_t)o * 8;
        *reinterpret_cast<short8*>(wt + base) = h;
    }
}

// -----------------------------------------------------------------------------
// Kernel 2: W-RESIDENT-IN-LDS GEMM (R15 skeleton) + DEPTH-3 A pipeline.
// One block per n (256 blocks, 512 threads = 8 waves, LDS-pinned 1 block/CU
// = 2 waves/SIMD). W[n] 128 KB + bias in LDS; ONE barrier; free-running waves
// own 128 rows (8 tiles of 16; 16 half-steps of 4 ks).
// FOUR f32 half-tile buffers F0..F3 (32 regs each): issue distance 3
// (~2100 cyc compute cover >= HBM latency; 24 loads in flight/wave).
// amdgpu_waves_per_eu(2,2) pins the unified budget to 256 (= what 1 block/CU
// already implies): arch ~155 + acc 64 AGPR fits. R20 decoded the accounting:
// unified budget INCLUDES AGPRs (waves_per_eu(4,4) -> 128 total -> 64 arch ->
// spill storm). Buffer selection via unrolled switch -> all indices static.
// -----------------------------------------------------------------------------
__global__ __launch_bounds__(512)
__attribute__((amdgpu_waves_per_eu(2, 2)))
void gemm_k(
    const float* __restrict__ x, const int* __restrict__ idx,
    const unsigned short* __restrict__ wt, const float* __restrict__ bias,
    float* __restrict__ out)
{
    __shared__ __align__(16) unsigned short Wl[WELEMS];   // 128 KB
    __shared__ __align__(16) float          Bl[256];      // 1 KB bias

    int n    = blockIdx.x;                 // 0..255, one n per block
    int tid  = threadIdx.x;
    int lane = tid & 63;
    int wv   = tid >> 6;                   // 0..7
    int r16  = lane & 15;
    int q    = lane >> 4;

    const unsigned short* wn = wt + (size_t)n * WELEMS;

    // ---- stage W[n]: 128 x 1KB linear DMA segments (16 per wave) ----
    #pragma unroll
    for (int j = 0; j < 16; ++j) {
        int g = wv * 16 + j;               // 0..127
        __builtin_amdgcn_global_load_lds(
            (const __attribute__((address_space(1))) void*)(wn + g * 512 + lane * 8),
            (__attribute__((address_space(3))) void*)(&Wl[g * 512]),
            16, 0, 0);
    }
    // ---- stage bias[c] ----
    int c = idx[n];
    if (tid < 64) {
        f32x4 b = *reinterpret_cast<const f32x4*>(bias + (size_t)c * OUT_SZ + tid * 4);
        *reinterpret_cast<f32x4*>(&Bl[tid * 4]) = b;
    }
    __syncthreads();   // the only barrier (drains DMA + ds_write)

    const float* xw = x + (size_t)n * (BATCH * IN_SZ)
                        + (size_t)(wv * 128 + r16) * IN_SZ + q * 8;
    float*       ow = out + (size_t)n * (BATCH * OUT_SZ)
                        + (size_t)(wv * 128 + r16) * OUT_SZ + q * 4;
    const char*  wl = reinterpret_cast<const char*>(Wl);
    int lq = q * 4096 + r16 * 16;          // lane's byte base into Wl (conflict-free)

    // Four HALF-TILE f32 buffers: 4 ks x 8 floats = 32 VGPR each.
    f32x4 F0[4][2], F1[4][2], F2[4][2], F3[4][2];

    // half-step s = 2*t + h  (t = 16-row chunk 0..7, h = ks-half)
    auto loadHalf = [&](f32x4 (&F)[4][2], int s) {
        const float* xp = xw + (size_t)(s >> 1) * 16 * IN_SZ + (s & 1) * 128;
        #pragma unroll
        for (int k = 0; k < 4; ++k) {
            F[k][0] = *reinterpret_cast<const f32x4*>(xp + k * 32);
            F[k][1] = *(reinterpret_cast<const f32x4*>(xp + k * 32) + 1);
        }
    };

    f32x4 acc[16];

    auto body = [&](int s, f32x4 (&Fc)[4][2], f32x4 (&Fn)[4][2]) {
        if ((s & 1) == 0) {                // new tile: acc init = bias
            #pragma unroll
            for (int nf = 0; nf < 16; ++nf)
                acc[nf] = *reinterpret_cast<const f32x4*>(&Bl[nf * 16 + q * 4]);
        }
        #pragma unroll
        for (int k = 0; k < 4; ++k) {
            int ks = (s & 1) * 4 + k;
            short8 af = cvt8(Fc[k][0], Fc[k][1]);
            #pragma unroll
            for (int nf = 0; nf < 16; ++nf) {
                short8 bf = *reinterpret_cast<const short8*>(
                    wl + lq + ks * 16384 + nf * 256);
                acc[nf] = __builtin_amdgcn_mfma_f32_16x16x32_bf16(
                    bf, af, acc[nf], 0, 0, 0);   // swapped: out^T frag
            }
        }
        if (s < 13) loadHalf(Fn, s + 3);   // refill buffer freed at s-1
        if (s & 1) {                       // tile finished: store 16 x 256
            float* op = ow + (size_t)(s >> 1) * 16 * OUT_SZ;
            #pragma unroll
            for (int nf = 0; nf < 16; ++nf)
                *reinterpret_cast<f32x4*>(op + nf * 16) = acc[nf];
        }
    };

    // prologue: 3 half-tiles in flight
    loadHalf(F0, 0);
    loadHalf(F1, 1);
    loadHalf(F2, 2);

    #pragma unroll
    for (int s = 0; s < 16; ++s) {
        switch (s & 3) {                   // static after unroll
            case 0: body(s, F0, F3); break;
            case 1: body(s, F1, F0); break;
            case 2: body(s, F2, F1); break;
            default: body(s, F3, F2); break;
        }
    }
}

extern "C" void kernel_launch(void* const* d_in, const int* in_sizes, int n_in,
                              void* d_out, int out_size, void* d_ws, size_t ws_size,
                              hipStream_t stream) {
    const float* x    = (const float*)d_in[0];
    const int*   idx  = (const int*)  d_in[1];
    const float* U    = (const float*)d_in[2];
    const float* V    = (const float*)d_in[3];
    const float* bias = (const float*)d_in[4];
    float* out = (float*)d_out;
    unsigned short* wt = (unsigned short*)d_ws;   // 32 MB scratch
    (void)in_sizes; (void)n_in; (void)out_size; (void)ws_size;

    synth_w<<<dim3(512), dim3(256), 0, stream>>>(U, V, idx, wt);
    gemm_k <<<dim3(256), dim3(512), 0, stream>>>(x, idx, wt, bias, out);
}